// Round 10
// baseline (429.064 us; speedup 1.0000x reference)
//
#include <hip/hip_runtime.h>
#include <math.h>

#define Bb 4
#define Cc 256
#define Nn 4096
#define Dd 32
#define XST 264   // proj x-tile LDS row stride (shorts)

typedef __attribute__((ext_vector_type(8))) short bf16x8;
typedef __attribute__((ext_vector_type(4))) float f32x4;

__device__ __forceinline__ unsigned short f2bf(float x) {
    union { float f; unsigned u; } c; c.f = x;
    unsigned r = c.u + 0x7fffu + ((c.u >> 16) & 1u);   // RNE
    return (unsigned short)(r >> 16);
}
__device__ __forceinline__ unsigned pk2(float a, float b) {
    return (unsigned)f2bf(a) | ((unsigned)f2bf(b) << 16);
}
__device__ __forceinline__ float fexp2(float x) {
#if __has_builtin(__builtin_amdgcn_exp2f)
    return __builtin_amdgcn_exp2f(x);
#else
    return __exp2f(x);
#endif
}
// Raw workgroup barrier: drain LDS ops only (p_s visibility), leave global
// loads (lane-private K/V prefetches) in flight across the barrier.
__device__ __forceinline__ void wg_barrier() {
    asm volatile("s_waitcnt lgkmcnt(0)\n\ts_barrier" ::: "memory");
}
// DPP sum over the 16-lane row (used ONCE, after the jt loop)
template <int CTRL>
__device__ __forceinline__ float dppf(float v) {
    int iv = __builtin_bit_cast(int, v);
    return __builtin_bit_cast(float,
        __builtin_amdgcn_update_dpp(iv, iv, CTRL, 0xF, 0xF, false));
}
__device__ __forceinline__ float rowsum16(float v) {
    v += dppf<0xB1>(v);    // quad xor1
    v += dppf<0x4E>(v);    // quad xor2
    v += dppf<0x141>(v);   // row_half_mirror
    v += dppf<0x140>(v);   // row_mirror
    return v;
}

// ---------------------------------------------------------------------------
// pack_w: W (q|k|v concat, 320 rows x 256) -> bf16 MFMA-fragment-major layout.
// Q rows pre-scaled by log2(e). grid 40 x 256.   (UNCHANGED)
// ---------------------------------------------------------------------------
__global__ __launch_bounds__(256) void pack_w(
    const float* __restrict__ qw, const float* __restrict__ kw,
    const float* __restrict__ vw, short* __restrict__ wpk) {
    const int g = blockIdx.x * 256 + threadIdx.x;   // 10240 frags
    const int qd = g & 3, m = (g >> 2) & 15, kc = (g >> 6) & 7, ot = g >> 9;
    const int o = 16 * ot + m;
    const float* src;
    float scale = 1.0f;
    if (o < 32)      { src = qw + (size_t)o * Cc; scale = 1.44269504088896f; }
    else if (o < 64) { src = kw + (size_t)(o - 32) * Cc; }
    else             { src = vw + (size_t)(o - 64) * Cc; }
    const float* s8 = src + 32 * kc + 8 * qd;
    uint4 u;
    u.x = pk2(s8[0] * scale, s8[1] * scale);
    u.y = pk2(s8[2] * scale, s8[3] * scale);
    u.z = pk2(s8[4] * scale, s8[5] * scale);
    u.w = pk2(s8[6] * scale, s8[7] * scale);
    *(uint4*)(wpk + (size_t)g * 8) = u;
}

// ---------------------------------------------------------------------------
// proj: qkv = W x, bf16 MFMA.  grid (Nn/32, 1, B) = 512 blocks, 256 thr.
// Outputs: q_t/k_t [b][n][32d]; V fragment-major (attn B-frag = base+lane*8).
// (UNCHANGED from round 3 — verified passing)
// ---------------------------------------------------------------------------
__global__ __launch_bounds__(256) void proj(
    const float* __restrict__ x, const short* __restrict__ wpk,
    short* __restrict__ q_t, short* __restrict__ k_t, short* __restrict__ v_b) {
    __shared__ alignas(16) short xs[32 * XST];   // 16.9 KB
    const int b = blockIdx.z;
    const int n0 = blockIdx.x * 32;
    const int tid = threadIdx.x;
    const int w = tid >> 6;
    const int lane = tid & 63, qd = lane >> 4, m = lane & 15;

    // ---- stage x^T tile (bf16): thread t covers n = t&31, c-range 32*(t>>5) ----
    {
        const int n = tid & 31, cg = tid >> 5;
        const float* xp = x + ((size_t)b * Cc + 32 * cg) * Nn + n0 + n;
        float xv[32];
#pragma unroll
        for (int i = 0; i < 32; ++i) xv[i] = xp[(size_t)i * Nn];
        short* row = xs + n * XST + 32 * cg;
#pragma unroll
        for (int u4 = 0; u4 < 4; ++u4)
            *(uint4*)(row + 8 * u4) = make_uint4(
                pk2(xv[8*u4+0], xv[8*u4+1]), pk2(xv[8*u4+2], xv[8*u4+3]),
                pk2(xv[8*u4+4], xv[8*u4+5]), pk2(xv[8*u4+6], xv[8*u4+7]));
    }
    __syncthreads();

    // ---- GEMM: wave w owns o-tiles ot = 4i + w ----
    const int fslot = m * 4 + qd;
    f32x4 acc[5][2];
#pragma unroll
    for (int i = 0; i < 5; ++i)
#pragma unroll
        for (int nt = 0; nt < 2; ++nt) acc[i][nt] = (f32x4){0.f, 0.f, 0.f, 0.f};

    bf16x8 afc[5], afn[5];
#pragma unroll
    for (int i = 0; i < 5; ++i)
        afc[i] = *(const bf16x8*)(wpk + ((size_t)((4*i + w) * 8 + 0) * 64 + fslot) * 8);

    for (int kc = 0; kc < 8; ++kc) {
        if (kc < 7) {
#pragma unroll
            for (int i = 0; i < 5; ++i)
                afn[i] = *(const bf16x8*)(
                    wpk + ((size_t)((4*i + w) * 8 + kc + 1) * 64 + fslot) * 8);
        }
        const bf16x8 b0 = *(const bf16x8*)&xs[(     m) * XST + 32 * kc + 8 * qd];
        const bf16x8 b1 = *(const bf16x8*)&xs[(16 + m) * XST + 32 * kc + 8 * qd];
#pragma unroll
        for (int i = 0; i < 5; ++i)
            acc[i][0] = __builtin_amdgcn_mfma_f32_16x16x32_bf16(afc[i], b0, acc[i][0], 0, 0, 0);
#pragma unroll
        for (int i = 0; i < 5; ++i)
            acc[i][1] = __builtin_amdgcn_mfma_f32_16x16x32_bf16(afc[i], b1, acc[i][1], 0, 0, 0);
#pragma unroll
        for (int i = 0; i < 5; ++i) afc[i] = afn[i];
    }

    // ---- epilogue: C row = 16*ot + 4*qd + rr, col n = n0 + 16*nt + m ----
#pragma unroll
    for (int i = 0; i < 5; ++i) {
        const int ot = 4 * i + w;
        if (ot < 4) {
            short* dst = (ot < 2 ? q_t : k_t) + (size_t)b * Nn * Dd;
            const int dbase = (ot & 1) * 16 + 4 * qd;
#pragma unroll
            for (int nt = 0; nt < 2; ++nt) {
                const f32x4 a = acc[i][nt];
                *(uint2*)(dst + (size_t)(n0 + 16 * nt + m) * Dd + dbase) =
                    make_uint2(pk2(a[0], a[1]), pk2(a[2], a[3]));
            }
        } else {
            // V fragment-major write: c = 16*(ot-4) + 4*qd + rr,
            // u32 covers slots s0 = 4m+2*b5, s0+1  (nt = 0,1).
            const int ct = ot - 4;
            const int jt = n0 >> 6;
            const int b5 = (n0 >> 5) & 1;
            const size_t vbase =
                (((size_t)(b * 64 + jt) * 32 + ct * 2 + (m >> 3)) * 64
                 + ((m >> 1) & 3) * 16 + 4 * qd) * 8 + 4 * (m & 1) + 2 * b5;
#pragma unroll
            for (int rr = 0; rr < 4; ++rr) {
                const unsigned pv = pk2(acc[i][0][rr], acc[i][1][rr]);
                *(unsigned*)(v_b + vbase + rr * 8) = pv;
            }
        }
    }
}

// ===========================================================================
// attn round-10: PRODUCER-CONSUMER wave specialization.
// 64 q-rows x 256 ch per block, 256 blocks x 512 thr (8 waves).
//   Waves 0-3 (producers): QK for rows 16w..16w+15 x ALL 64 keys (4 MFMA,
//     round-0-verified), exp2, l partials, round-0-verified contiguous
//     uint2 kappa write (cols 4m..4m+3 = nt 0..3).
//   Waves 4-7 (consumers): PV only, 64 channels each (8 V-frags, 32 MFMA,
//     8 b128 p-reads). LDS p-read amplification halves (4 readers not 8).
//   One lgkm-barrier per tile: producers fill buf[(t+1)&1] while consumers
//   drain buf[t&1]; WAR separated by the intervening barrier (same proof
//   as rounds 4-9). Per SIMD: 1 VALU-heavy producer + 1 MFMA-heavy
//   consumer co-issue (m114). K prefetch 2 tiles ahead (producers), V 1
//   tile ahead (consumers), register ping-pong, setprio around PV.
// LDS: buf0 @0, buf1 @9216 (9216B each); l_s [64] f32 @18432;
//      epilogue o_t [64][68] f32 overlay @0 (17408B). pool 18688B.
// ===========================================================================
__device__ __forceinline__ void produce(
    const bf16x8 af, bf16x8 bk[4], const short* kpre, bool pre,
    short* psbuf, float* l_i, int w, int qd, int m) {
    f32x4 s[4];
#pragma unroll
    for (int nt = 0; nt < 4; ++nt)
        s[nt] = __builtin_amdgcn_mfma_f32_16x16x32_bf16(
            af, bk[nt], (f32x4){0.f, 0.f, 0.f, 0.f}, 0, 0, 0);
    if (pre) {
#pragma unroll
        for (int nt = 0; nt < 4; ++nt)
            bk[nt] = *(const bf16x8*)(kpre + nt * 512);
    }
#pragma unroll
    for (int rr = 0; rr < 4; ++rr) {
        const float p0 = fexp2(s[0][rr]);
        const float p1 = fexp2(s[1][rr]);
        const float p2 = fexp2(s[2][rr]);
        const float p3 = fexp2(s[3][rr]);
        l_i[rr] += (p0 + p1) + (p2 + p3);
        *(uint2*)&psbuf[(16 * w + 4 * qd + rr) * 72 + 4 * m] =
            make_uint2(pk2(p0, p1), pk2(p2, p3));
    }
}

__device__ __forceinline__ void consume(
    const short* psbuf, const bf16x8* vf, f32x4* oacc, int qd, int m) {
#pragma unroll
    for (int kc = 0; kc < 2; ++kc) {
        bf16x8 pa[4];
#pragma unroll
        for (int mt = 0; mt < 4; ++mt)
            pa[mt] = *(const bf16x8*)&psbuf[(16 * mt + m) * 72 + 32 * kc + 8 * qd];
#pragma unroll
        for (int ct = 0; ct < 4; ++ct)
#pragma unroll
            for (int mt = 0; mt < 4; ++mt)
                oacc[4 * mt + ct] = __builtin_amdgcn_mfma_f32_16x16x32_bf16(
                    pa[mt], vf[2 * ct + kc], oacc[4 * mt + ct], 0, 0, 0);
    }
}

__global__ __launch_bounds__(512) void attn(
    const float* __restrict__ x, const short* __restrict__ q_t,
    const short* __restrict__ k_t, const short* __restrict__ v_b,
    const float* __restrict__ gamma, float* __restrict__ out) {
    __shared__ alignas(16) char pool[18688];
    short* buf0 = (short*)pool;             // p_s parity 0 (even tiles)
    short* buf1 = (short*)(pool + 9216);    // p_s parity 1 (odd tiles)
    float* l_s  = (float*)(pool + 18432);   // [64] f32 (full row sums)
    float* o_t  = (float*)pool;             // [64][68] f32 epilogue overlay

    const int fb  = blockIdx.x;             // 0..255
    const int xcd = fb & 7;
    const int b   = xcd >> 1;
    const int i0  = (((xcd & 1) << 5) | (fb >> 3)) << 6;
    const int tid = threadIdx.x;
    const int w = tid >> 6, lane = tid & 63;
    const int qd = lane >> 4, m = lane & 15;
    const bool isProd = (w < 4);

    bf16x8 af;                 // producer: Q-frag rows 16w+m
    bf16x8 bkA[4], bkB[4];     // producer: K frags (even/odd tile sets)
    bf16x8 vfA[8], vfB[8];     // consumer: V frags (even/odd tile sets)
    f32x4 oacc[16];            // consumer: [4 mt][4 ct]
    float l_i[4] = {0.f, 0.f, 0.f, 0.f};

    const short* kf = k_t + (size_t)b * Nn * Dd + m * Dd + 8 * qd;   // producer
    const short* vw = v_b + (size_t)b * (64 * 32 * 64 * 8)
                    + (size_t)(8 * (w - 4)) * 512 + lane * 8;        // consumer

    // ---- prologue ----
    if (isProd) {
        af = *(const bf16x8*)(q_t + ((size_t)b * Nn + i0 + 16 * w + m) * Dd + 8 * qd);
#pragma unroll
        for (int nt = 0; nt < 4; ++nt)
            bkA[nt] = *(const bf16x8*)(kf + nt * 512);               // K(0)
        produce(af, bkA, kf + 4096, true, buf0, l_i, w, qd, m);      // QK(0); bkA<-K(2)
#pragma unroll
        for (int nt = 0; nt < 4; ++nt)
            bkB[nt] = *(const bf16x8*)(kf + 2048 + nt * 512);        // K(1)
    } else {
#pragma unroll
        for (int i = 0; i < 8; ++i)
            vfA[i] = *(const bf16x8*)(vw + i * 512);                 // V(0)
#pragma unroll
        for (int i = 0; i < 16; ++i) oacc[i] = (f32x4){0.f, 0.f, 0.f, 0.f};
    }
    wg_barrier();   // buf0 (tile 0) visible

    const short* kpre = kf + 3 * 2048;   // K(2j2+3) in phase A
    const short* vpre = vw + 16384;      // V(2j2+1) in phase A

    for (int j2 = 0; j2 < 31; ++j2) {
        // ===== phase A (t=2j2): produce QK(2j2+1)->buf1 ; consume PV(2j2) buf0/vfA =====
        if (isProd) {
            produce(af, bkB, kpre, true, buf1, l_i, w, qd, m);       // bkB<-K(2j2+3)
        } else {
#pragma unroll
            for (int i = 0; i < 8; ++i)
                vfB[i] = *(const bf16x8*)(vpre + i * 512);           // V(2j2+1)
            __builtin_amdgcn_s_setprio(1);
            consume(buf0, vfA, oacc, qd, m);
            __builtin_amdgcn_s_setprio(0);
        }
        wg_barrier();
        // ===== phase B (t=2j2+1): produce QK(2j2+2)->buf0 ; consume PV(2j2+1) buf1/vfB =====
        if (isProd) {
            produce(af, bkA, kpre + 2048, j2 < 30, buf0, l_i, w, qd, m);  // bkA<-K(2j2+4)
        } else {
#pragma unroll
            for (int i = 0; i < 8; ++i)
                vfA[i] = *(const bf16x8*)(vpre + 16384 + i * 512);   // V(2j2+2)
            __builtin_amdgcn_s_setprio(1);
            consume(buf1, vfB, oacc, qd, m);
            __builtin_amdgcn_s_setprio(0);
        }
        wg_barrier();
        kpre += 4096;
        vpre += 32768;
    }

    // ---- phase 62: produce QK(63)->buf1 ; consume PV(62) buf0/vfA ----
    if (isProd) {
        produce(af, bkB, kf, false, buf1, l_i, w, qd, m);
    } else {
#pragma unroll
        for (int i = 0; i < 8; ++i)
            vfB[i] = *(const bf16x8*)(vpre + i * 512);               // V(63)
        __builtin_amdgcn_s_setprio(1);
        consume(buf0, vfA, oacc, qd, m);
        __builtin_amdgcn_s_setprio(0);
    }
    wg_barrier();
    // ---- tail: consume PV(63) buf1/vfB ----
    if (!isProd) {
        __builtin_amdgcn_s_setprio(1);
        consume(buf1, vfB, oacc, qd, m);
        __builtin_amdgcn_s_setprio(0);
    }

    // ---- l reduction (producers own full row sums) ----
    if (isProd) {
#pragma unroll
        for (int rr = 0; rr < 4; ++rr) l_i[rr] = rowsum16(l_i[rr]);
        if (m == 0)
            *(f32x4*)&l_s[16 * w + 4 * qd] = (f32x4){l_i[0], l_i[1], l_i[2], l_i[3]};
    }
    __syncthreads();   // all loop LDS reads drained; l_s visible; o_t overlay safe

    // ---- epilogue: 4 passes of 64 ch-cols via o_t overlay ----
    const float g = gamma[0];
    const int i = tid & 63, cg8 = tid >> 6;
    const float linv = 1.0f / l_s[i];
#pragma unroll
    for (int ps = 0; ps < 4; ++ps) {
        if (ps) __syncthreads();
        if (!isProd) {
            const int wp = w - 4;
#pragma unroll
            for (int mt = 0; mt < 4; ++mt)
#pragma unroll
                for (int rr = 0; rr < 4; ++rr)
                    o_t[(16 * mt + 4 * qd + rr) * 68 + 16 * wp + m] =
                        oacc[4 * mt + ps][rr];
        }
        __syncthreads();
#pragma unroll
        for (int u = 0; u < 2; ++u) {
            const f32x4 v4 = *(const f32x4*)&o_t[i * 68 + 8 * cg8 + 4 * u];
#pragma unroll
            for (int e = 0; e < 4; ++e) {
                const int cc = 8 * cg8 + 4 * u + e;
                const int c = 64 * (cc >> 4) + 16 * ps + (cc & 15);
                const size_t gidx = ((size_t)b * Cc + c) * Nn + i0 + i;
                out[gidx] = g * v4[e] * linv + x[gidx];
            }
        }
    }
}

// ---------------------------------------------------------------------------
extern "C" void kernel_launch(void* const* d_in, const int* in_sizes, int n_in,
                              void* d_out, int out_size, void* d_ws, size_t ws_size,
                              hipStream_t stream) {
    const float* x     = (const float*)d_in[0];
    const float* qw    = (const float*)d_in[1];
    const float* kw    = (const float*)d_in[2];
    const float* vw    = (const float*)d_in[3];
    const float* gamma = (const float*)d_in[4];
    float* out = (float*)d_out;

    short* q_t = (short*)d_ws;                       // [b][n][32] bf16, 1 MB
    short* k_t = q_t + (size_t)Bb * Nn * Dd;         // [b][n][32] bf16, 1 MB
    short* v_b = k_t + (size_t)Bb * Nn * Dd;         // fragment-major V, 8.4 MB
    short* wpk = v_b + (size_t)Bb * Cc * Nn;         // 160 KB packed W

    pack_w<<<dim3(40), 256, 0, stream>>>(qw, kw, vw, wpk);
    proj<<<dim3(Nn / 32, 1, Bb), 256, 0, stream>>>(x, wpk, q_t, k_t, v_b);
    attn<<<dim3(256), 512, 0, stream>>>(x, q_t, k_t, v_b, gamma, out);
}

// Round 11
// 133.832 us; speedup vs baseline: 3.2060x; 3.2060x over previous
//
#include <hip/hip_runtime.h>
#include <math.h>

#define Bb 4
#define Cc 256
#define Nn 4096
#define Dd 32
#define XST 264   // proj x-tile LDS row stride (shorts)

typedef __attribute__((ext_vector_type(8))) short bf16x8;
typedef __attribute__((ext_vector_type(4))) float f32x4;

__device__ __forceinline__ unsigned short f2bf(float x) {
    union { float f; unsigned u; } c; c.f = x;
    unsigned r = c.u + 0x7fffu + ((c.u >> 16) & 1u);   // RNE
    return (unsigned short)(r >> 16);
}
__device__ __forceinline__ unsigned pk2(float a, float b) {
    return (unsigned)f2bf(a) | ((unsigned)f2bf(b) << 16);
}
__device__ __forceinline__ float fexp2(float x) {
#if __has_builtin(__builtin_amdgcn_exp2f)
    return __builtin_amdgcn_exp2f(x);
#else
    return __exp2f(x);
#endif
}
// Raw workgroup barrier: drain LDS ops only (p_s visibility), leave global
// loads (lane-private K/V prefetches) in flight across the barrier.
__device__ __forceinline__ void wg_barrier() {
    asm volatile("s_waitcnt lgkmcnt(0)\n\ts_barrier" ::: "memory");
}
// DPP sum over the 16-lane row (used ONCE, after the jt loop)
template <int CTRL>
__device__ __forceinline__ float dppf(float v) {
    int iv = __builtin_bit_cast(int, v);
    return __builtin_bit_cast(float,
        __builtin_amdgcn_update_dpp(iv, iv, CTRL, 0xF, 0xF, false));
}
__device__ __forceinline__ float rowsum16(float v) {
    v += dppf<0xB1>(v);    // quad xor1
    v += dppf<0x4E>(v);    // quad xor2
    v += dppf<0x141>(v);   // row_half_mirror
    v += dppf<0x140>(v);   // row_mirror
    return v;
}

// ---------------------------------------------------------------------------
// pack_w: W (q|k|v concat, 320 rows x 256) -> bf16 MFMA-fragment-major layout.
// Q rows pre-scaled by log2(e). grid 40 x 256.   (UNCHANGED)
// ---------------------------------------------------------------------------
__global__ __launch_bounds__(256) void pack_w(
    const float* __restrict__ qw, const float* __restrict__ kw,
    const float* __restrict__ vw, short* __restrict__ wpk) {
    const int g = blockIdx.x * 256 + threadIdx.x;   // 10240 frags
    const int qd = g & 3, m = (g >> 2) & 15, kc = (g >> 6) & 7, ot = g >> 9;
    const int o = 16 * ot + m;
    const float* src;
    float scale = 1.0f;
    if (o < 32)      { src = qw + (size_t)o * Cc; scale = 1.44269504088896f; }
    else if (o < 64) { src = kw + (size_t)(o - 32) * Cc; }
    else             { src = vw + (size_t)(o - 64) * Cc; }
    const float* s8 = src + 32 * kc + 8 * qd;
    uint4 u;
    u.x = pk2(s8[0] * scale, s8[1] * scale);
    u.y = pk2(s8[2] * scale, s8[3] * scale);
    u.z = pk2(s8[4] * scale, s8[5] * scale);
    u.w = pk2(s8[6] * scale, s8[7] * scale);
    *(uint4*)(wpk + (size_t)g * 8) = u;
}

// ---------------------------------------------------------------------------
// proj round-11: n-tile-64 block (grid (Nn/64,1,B) = 256 blocks, 256 thr).
// Runs the VERBATIM round-3 proj body twice (half = 0,1; n0 = 64*jt+32*half;
// b5 = half). The only change: V-epilogue stores go to LDS vstage (identical
// index formula minus the global base); after a barrier the block dumps its
// fully-contiguous 32 KB v_pk[b][jt] region with coalesced uint4 stores.
// q_t/k_t epilogue unchanged. xs re-staged per half (barrier-protected).
// LDS 49.7 KB -> 2 blocks/CU.
// ---------------------------------------------------------------------------
__global__ __launch_bounds__(256) void proj(
    const float* __restrict__ x, const short* __restrict__ wpk,
    short* __restrict__ q_t, short* __restrict__ k_t, short* __restrict__ v_b) {
    __shared__ alignas(16) short xs[32 * XST];   // 16.9 KB
    __shared__ alignas(16) short vstage[16384];  // 32 KB (one full 64-group)
    const int b = blockIdx.z;
    const int jt = blockIdx.x;
    const int tid = threadIdx.x;
    const int w = tid >> 6;
    const int lane = tid & 63, qd = lane >> 4, m = lane & 15;

    for (int half = 0; half < 2; ++half) {
        const int n0 = jt * 64 + half * 32;
        if (half) __syncthreads();   // prior half's xs reads + epilogue done

        // ---- stage x^T tile (bf16): thread t covers n = t&31, c-range 32*(t>>5) ----
        {
            const int n = tid & 31, cg = tid >> 5;
            const float* xp = x + ((size_t)b * Cc + 32 * cg) * Nn + n0 + n;
            float xv[32];
#pragma unroll
            for (int i = 0; i < 32; ++i) xv[i] = xp[(size_t)i * Nn];
            short* row = xs + n * XST + 32 * cg;
#pragma unroll
            for (int u4 = 0; u4 < 4; ++u4)
                *(uint4*)(row + 8 * u4) = make_uint4(
                    pk2(xv[8*u4+0], xv[8*u4+1]), pk2(xv[8*u4+2], xv[8*u4+3]),
                    pk2(xv[8*u4+4], xv[8*u4+5]), pk2(xv[8*u4+6], xv[8*u4+7]));
        }
        __syncthreads();

        // ---- GEMM: wave w owns o-tiles ot = 4i + w ----
        const int fslot = m * 4 + qd;
        f32x4 acc[5][2];
#pragma unroll
        for (int i = 0; i < 5; ++i)
#pragma unroll
            for (int nt = 0; nt < 2; ++nt) acc[i][nt] = (f32x4){0.f, 0.f, 0.f, 0.f};

        bf16x8 afc[5], afn[5];
#pragma unroll
        for (int i = 0; i < 5; ++i)
            afc[i] = *(const bf16x8*)(wpk + ((size_t)((4*i + w) * 8 + 0) * 64 + fslot) * 8);

        for (int kc = 0; kc < 8; ++kc) {
            if (kc < 7) {
#pragma unroll
                for (int i = 0; i < 5; ++i)
                    afn[i] = *(const bf16x8*)(
                        wpk + ((size_t)((4*i + w) * 8 + kc + 1) * 64 + fslot) * 8);
            }
            const bf16x8 b0 = *(const bf16x8*)&xs[(     m) * XST + 32 * kc + 8 * qd];
            const bf16x8 b1 = *(const bf16x8*)&xs[(16 + m) * XST + 32 * kc + 8 * qd];
#pragma unroll
            for (int i = 0; i < 5; ++i)
                acc[i][0] = __builtin_amdgcn_mfma_f32_16x16x32_bf16(afc[i], b0, acc[i][0], 0, 0, 0);
#pragma unroll
            for (int i = 0; i < 5; ++i)
                acc[i][1] = __builtin_amdgcn_mfma_f32_16x16x32_bf16(afc[i], b1, acc[i][1], 0, 0, 0);
#pragma unroll
            for (int i = 0; i < 5; ++i) afc[i] = afn[i];
        }

        // ---- epilogue: C row = 16*ot + 4*qd + rr, col n = n0 + 16*nt + m ----
#pragma unroll
        for (int i = 0; i < 5; ++i) {
            const int ot = 4 * i + w;
            if (ot < 4) {
                short* dst = (ot < 2 ? q_t : k_t) + (size_t)b * Nn * Dd;
                const int dbase = (ot & 1) * 16 + 4 * qd;
#pragma unroll
                for (int nt = 0; nt < 2; ++nt) {
                    const f32x4 a = acc[i][nt];
                    *(uint2*)(dst + (size_t)(n0 + 16 * nt + m) * Dd + dbase) =
                        make_uint2(pk2(a[0], a[1]), pk2(a[2], a[3]));
                }
            } else {
                // V write -> LDS stage (identical formula minus global base)
                const int ct = ot - 4;
                const int b5 = half;
                const int vbase =
                    ((ct * 2 + (m >> 3)) * 64 + ((m >> 1) & 3) * 16 + 4 * qd) * 8
                    + 4 * (m & 1) + 2 * b5;
#pragma unroll
                for (int rr = 0; rr < 4; ++rr) {
                    const unsigned pv = pk2(acc[i][0][rr], acc[i][1][rr]);
                    *(unsigned*)(vstage + vbase + rr * 8) = pv;
                }
            }
        }
    }
    __syncthreads();   // vstage complete (both halves)

    // ---- coalesced dump: 32 KB contiguous v_pk[b][jt] ----
    {
        uint4* dst = (uint4*)(v_b + (size_t)(b * 64 + jt) * 16384);
        const uint4* srcv = (const uint4*)vstage;
#pragma unroll
        for (int i = 0; i < 8; ++i)
            dst[tid + 256 * i] = srcv[tid + 256 * i];
    }
}

// ---------------------------------------------------------------------------
// attn: EXACT round-9 kernel (verified 54.1 us). Flash attention, 64 q-rows
// x 256 ch, 256 blocks x 512 thr (8 waves), intra-phase software pipeline:
// phase(j) = { QK(j+1) MFMA ; PV(j) from p_s[cur] ; exp(j+1) ; write
// p_s[nxt] ; lgkm-barrier }. K prefetch 2 tiles ahead, V 1 phase ahead.
// ---------------------------------------------------------------------------
__global__ __launch_bounds__(512) void attn(
    const float* __restrict__ x, const short* __restrict__ q_t,
    const short* __restrict__ k_t, const short* __restrict__ v_b,
    const float* __restrict__ gamma, float* __restrict__ out) {
    __shared__ alignas(16) char pool[34304];
    float* l_s = (float*)(pool + 33792);    // [2][64] f32
    float* o_t = (float*)pool;              // [64][132] f32 epilogue overlay
    short* buf0 = (short*)pool;             // p_s parity 0 (even tiles)
    short* buf1 = (short*)(pool + 9216);    // p_s parity 1 (odd tiles)

    const int fb  = blockIdx.x;             // 0..255
    const int xcd = fb & 7;
    const int b   = xcd >> 1;
    const int i0  = (((xcd & 1) << 5) | (fb >> 3)) << 6;
    const int tid = threadIdx.x;
    const int w = tid >> 6, lane = tid & 63;
    const int qd = lane >> 4, m = lane & 15;
    const int rt = w & 3, kh = w >> 2;

    // loop-invariant Q fragment (rows i0+16rt+m)
    const bf16x8 af = *(const bf16x8*)(
        q_t + ((size_t)b * Nn + i0 + 16 * rt + m) * Dd + 8 * qd);

    // K frag base: tile jt at kf + jt*2048 (+512 for second 16-key subtile)
    const short* kf = k_t + (size_t)b * Nn * Dd + (32 * kh + m) * Dd + 8 * qd;
    // V frag base: wave w owns frag-groups 4w..4w+3; tile jt at +jt*16384
    const short* vw = v_b + (size_t)b * (64 * 32 * 64 * 8) + (4 * w) * 512 + lane * 8;

    // prologue loads: K(0),K(1); V(0)
    bf16x8 bkA0 = *(const bf16x8*)(kf);
    bf16x8 bkA1 = *(const bf16x8*)(kf + 512);
    bf16x8 bkB0 = *(const bf16x8*)(kf + 2048);
    bf16x8 bkB1 = *(const bf16x8*)(kf + 2560);
    bf16x8 vfA[2][2], vfB[2][2];
#pragma unroll
    for (int ct = 0; ct < 2; ++ct)
#pragma unroll
        for (int kc = 0; kc < 2; ++kc)
            vfA[ct][kc] = *(const bf16x8*)(vw + (2 * ct + kc) * 512);

    f32x4 oacc[4][2];
#pragma unroll
    for (int mt = 0; mt < 4; ++mt)
#pragma unroll
        for (int ct = 0; ct < 2; ++ct) oacc[mt][ct] = (f32x4){0.f, 0.f, 0.f, 0.f};
    float l_i[4] = {0.f, 0.f, 0.f, 0.f};

    // ---- prologue: QK(0) + exp -> buf0 ----
    {
        const f32x4 s0 = __builtin_amdgcn_mfma_f32_16x16x32_bf16(
            af, bkA0, (f32x4){0.f, 0.f, 0.f, 0.f}, 0, 0, 0);
        const f32x4 s1 = __builtin_amdgcn_mfma_f32_16x16x32_bf16(
            af, bkA1, (f32x4){0.f, 0.f, 0.f, 0.f}, 0, 0, 0);
        bkA0 = *(const bf16x8*)(kf + 4096);          // K(2)
        bkA1 = *(const bf16x8*)(kf + 4096 + 512);
#pragma unroll
        for (int rr = 0; rr < 4; ++rr) {
            const float p0 = fexp2(s0[rr]);
            const float p1 = fexp2(s1[rr]);
            l_i[rr] += p0 + p1;
            *(unsigned*)&buf0[(16 * rt + 4 * qd + rr) * 72 + 4 * m + 2 * kh] =
                pk2(p0, p1);
        }
        wg_barrier();
    }

    const short* kpre = kf + 3 * 2048;   // K(2j2+3) in phase A
    const short* vpre = vw + 16384;      // V(2j2+1) in phase A

    for (int j2 = 0; j2 < 31; ++j2) {
        // ===== phase A: QK(2j2+1) ; PV(2j2) buf0/vfA ; exp -> buf1 =====
        {
            const f32x4 s0 = __builtin_amdgcn_mfma_f32_16x16x32_bf16(
                af, bkB0, (f32x4){0.f, 0.f, 0.f, 0.f}, 0, 0, 0);
            const f32x4 s1 = __builtin_amdgcn_mfma_f32_16x16x32_bf16(
                af, bkB1, (f32x4){0.f, 0.f, 0.f, 0.f}, 0, 0, 0);
            bkB0 = *(const bf16x8*)(kpre);           // K(2j2+3)
            bkB1 = *(const bf16x8*)(kpre + 512);
#pragma unroll
            for (int ct = 0; ct < 2; ++ct)           // V(2j2+1) -> vfB
#pragma unroll
                for (int kc = 0; kc < 2; ++kc)
                    vfB[ct][kc] = *(const bf16x8*)(vpre + (2 * ct + kc) * 512);
            __builtin_amdgcn_s_setprio(1);
#pragma unroll
            for (int kc = 0; kc < 2; ++kc) {         // PV(2j2)
                bf16x8 pa[4];
#pragma unroll
                for (int mt = 0; mt < 4; ++mt)
                    pa[mt] = *(const bf16x8*)&buf0[(16 * mt + m) * 72 + 32 * kc + 8 * qd];
#pragma unroll
                for (int ct = 0; ct < 2; ++ct)
#pragma unroll
                    for (int mt = 0; mt < 4; ++mt)
                        oacc[mt][ct] = __builtin_amdgcn_mfma_f32_16x16x32_bf16(
                            pa[mt], vfA[ct][kc], oacc[mt][ct], 0, 0, 0);
            }
            __builtin_amdgcn_s_setprio(0);
#pragma unroll
            for (int rr = 0; rr < 4; ++rr) {         // exp(2j2+1) -> buf1
                const float p0 = fexp2(s0[rr]);
                const float p1 = fexp2(s1[rr]);
                l_i[rr] += p0 + p1;
                *(unsigned*)&buf1[(16 * rt + 4 * qd + rr) * 72 + 4 * m + 2 * kh] =
                    pk2(p0, p1);
            }
            wg_barrier();
        }
        // ===== phase B: QK(2j2+2) ; PV(2j2+1) buf1/vfB ; exp -> buf0 =====
        {
            const f32x4 s0 = __builtin_amdgcn_mfma_f32_16x16x32_bf16(
                af, bkA0, (f32x4){0.f, 0.f, 0.f, 0.f}, 0, 0, 0);
            const f32x4 s1 = __builtin_amdgcn_mfma_f32_16x16x32_bf16(
                af, bkA1, (f32x4){0.f, 0.f, 0.f, 0.f}, 0, 0, 0);
            if (j2 < 30) {                           // K(2j2+4) (skip OOB tail)
                bkA0 = *(const bf16x8*)(kpre + 2048);
                bkA1 = *(const bf16x8*)(kpre + 2560);
            }
#pragma unroll
            for (int ct = 0; ct < 2; ++ct)           // V(2j2+2) -> vfA
#pragma unroll
                for (int kc = 0; kc < 2; ++kc)
                    vfA[ct][kc] = *(const bf16x8*)(vpre + 16384 + (2 * ct + kc) * 512);
            __builtin_amdgcn_s_setprio(1);
#pragma unroll
            for (int kc = 0; kc < 2; ++kc) {         // PV(2j2+1)
                bf16x8 pa[4];
#pragma unroll
                for (int mt = 0; mt < 4; ++mt)
                    pa[mt] = *(const bf16x8*)&buf1[(16 * mt + m) * 72 + 32 * kc + 8 * qd];
#pragma unroll
                for (int ct = 0; ct < 2; ++ct)
#pragma unroll
                    for (int mt = 0; mt < 4; ++mt)
                        oacc[mt][ct] = __builtin_amdgcn_mfma_f32_16x16x32_bf16(
                            pa[mt], vfB[ct][kc], oacc[mt][ct], 0, 0, 0);
            }
            __builtin_amdgcn_s_setprio(0);
#pragma unroll
            for (int rr = 0; rr < 4; ++rr) {         // exp(2j2+2) -> buf0
                const float p0 = fexp2(s0[rr]);
                const float p1 = fexp2(s1[rr]);
                l_i[rr] += p0 + p1;
                *(unsigned*)&buf0[(16 * rt + 4 * qd + rr) * 72 + 4 * m + 2 * kh] =
                    pk2(p0, p1);
            }
            wg_barrier();
        }
        kpre += 4096;
        vpre += 32768;
    }

    // ---- tail A: QK(63) ; PV(62) buf0/vfA ; exp -> buf1 ----
    {
        const f32x4 s0 = __builtin_amdgcn_mfma_f32_16x16x32_bf16(
            af, bkB0, (f32x4){0.f, 0.f, 0.f, 0.f}, 0, 0, 0);
        const f32x4 s1 = __builtin_amdgcn_mfma_f32_16x16x32_bf16(
            af, bkB1, (f32x4){0.f, 0.f, 0.f, 0.f}, 0, 0, 0);
#pragma unroll
        for (int ct = 0; ct < 2; ++ct)               // V(63) -> vfB
#pragma unroll
            for (int kc = 0; kc < 2; ++kc)
                vfB[ct][kc] = *(const bf16x8*)(vpre + (2 * ct + kc) * 512);
        __builtin_amdgcn_s_setprio(1);
#pragma unroll
        for (int kc = 0; kc < 2; ++kc) {             // PV(62)
            bf16x8 pa[4];
#pragma unroll
            for (int mt = 0; mt < 4; ++mt)
                pa[mt] = *(const bf16x8*)&buf0[(16 * mt + m) * 72 + 32 * kc + 8 * qd];
#pragma unroll
            for (int ct = 0; ct < 2; ++ct)
#pragma unroll
                for (int mt = 0; mt < 4; ++mt)
                    oacc[mt][ct] = __builtin_amdgcn_mfma_f32_16x16x32_bf16(
                        pa[mt], vfA[ct][kc], oacc[mt][ct], 0, 0, 0);
        }
        __builtin_amdgcn_s_setprio(0);
#pragma unroll
        for (int rr = 0; rr < 4; ++rr) {             // exp(63) -> buf1
            const float p0 = fexp2(s0[rr]);
            const float p1 = fexp2(s1[rr]);
            l_i[rr] += p0 + p1;
            *(unsigned*)&buf1[(16 * rt + 4 * qd + rr) * 72 + 4 * m + 2 * kh] =
                pk2(p0, p1);
        }
        wg_barrier();
    }
    // ---- tail B: PV(63) buf1/vfB ----
    {
        __builtin_amdgcn_s_setprio(1);
#pragma unroll
        for (int kc = 0; kc < 2; ++kc) {
            bf16x8 pa[4];
#pragma unroll
            for (int mt = 0; mt < 4; ++mt)
                pa[mt] = *(const bf16x8*)&buf1[(16 * mt + m) * 72 + 32 * kc + 8 * qd];
#pragma unroll
            for (int ct = 0; ct < 2; ++ct)
#pragma unroll
                for (int mt = 0; mt < 4; ++mt)
                    oacc[mt][ct] = __builtin_amdgcn_mfma_f32_16x16x32_bf16(
                        pa[mt], vfB[ct][kc], oacc[mt][ct], 0, 0, 0);
        }
        __builtin_amdgcn_s_setprio(0);
    }

    // final l reduction: per kh-half row sums, combined in epilogue
#pragma unroll
    for (int rr = 0; rr < 4; ++rr) l_i[rr] = rowsum16(l_i[rr]);
    if (m == 0)
        *(f32x4*)&l_s[kh * 64 + 16 * rt + 4 * qd] =
            (f32x4){l_i[0], l_i[1], l_i[2], l_i[3]};
    __syncthreads();   // l published; loop LDS dead -> o_t overlay safe

    // ---- epilogue: transpose O via LDS overlay, out = gamma*O/l + x ----
    const float g = gamma[0];
    const int i = tid & 63, cg8 = tid >> 6;   // row, ch-group
    const float linv = 1.0f / (l_s[i] + l_s[64 + i]);
#pragma unroll
    for (int ps = 0; ps < 2; ++ps) {
        if (ps) __syncthreads();
        // pass ps: channels 32w + 16ps + m  -> compact col cc = 16w + m
#pragma unroll
        for (int mt = 0; mt < 4; ++mt)
#pragma unroll
            for (int rr = 0; rr < 4; ++rr)
                o_t[(16 * mt + 4 * qd + rr) * 132 + 16 * w + m] = oacc[mt][ps][rr];
        __syncthreads();
#pragma unroll
        for (int u = 0; u < 4; ++u) {
            const f32x4 v4 = *(const f32x4*)&o_t[i * 132 + 16 * cg8 + 4 * u];
#pragma unroll
            for (int e = 0; e < 4; ++e) {
                const int c = 32 * cg8 + 16 * ps + 4 * u + e;
                const size_t gidx = ((size_t)b * Cc + c) * Nn + i0 + i;
                out[gidx] = g * v4[e] * linv + x[gidx];
            }
        }
    }
}

// ---------------------------------------------------------------------------
extern "C" void kernel_launch(void* const* d_in, const int* in_sizes, int n_in,
                              void* d_out, int out_size, void* d_ws, size_t ws_size,
                              hipStream_t stream) {
    const float* x     = (const float*)d_in[0];
    const float* qw    = (const float*)d_in[1];
    const float* kw    = (const float*)d_in[2];
    const float* vw    = (const float*)d_in[3];
    const float* gamma = (const float*)d_in[4];
    float* out = (float*)d_out;

    short* q_t = (short*)d_ws;                       // [b][n][32] bf16, 1 MB
    short* k_t = q_t + (size_t)Bb * Nn * Dd;         // [b][n][32] bf16, 1 MB
    short* v_b = k_t + (size_t)Bb * Nn * Dd;         // fragment-major V, 8.4 MB
    short* wpk = v_b + (size_t)Bb * Cc * Nn;         // 160 KB packed W

    pack_w<<<dim3(40), 256, 0, stream>>>(qw, kw, vw, wpk);
    proj<<<dim3(Nn / 64, 1, Bb), 256, 0, stream>>>(x, wpk, q_t, k_t, v_b);
    attn<<<dim3(256), 512, 0, stream>>>(x, q_t, k_t, v_b, gamma, out);
}

// Round 12
// 130.464 us; speedup vs baseline: 3.2887x; 1.0258x over previous
//
#include <hip/hip_runtime.h>
#include <math.h>

#define Bb 4
#define Cc 256
#define Nn 4096
#define Dd 32
#define XST 264   // proj x-tile LDS row stride (shorts)

typedef __attribute__((ext_vector_type(8))) short bf16x8;
typedef __attribute__((ext_vector_type(4))) float f32x4;

__device__ __forceinline__ unsigned short f2bf(float x) {
    union { float f; unsigned u; } c; c.f = x;
    unsigned r = c.u + 0x7fffu + ((c.u >> 16) & 1u);   // RNE
    return (unsigned short)(r >> 16);
}
__device__ __forceinline__ unsigned pk2(float a, float b) {
    return (unsigned)f2bf(a) | ((unsigned)f2bf(b) << 16);
}
__device__ __forceinline__ float fexp2(float x) {
#if __has_builtin(__builtin_amdgcn_exp2f)
    return __builtin_amdgcn_exp2f(x);
#else
    return __exp2f(x);
#endif
}
// Raw workgroup barrier: drain LDS ops only (p_s visibility), leave global
// loads (lane-private K/V prefetches) in flight across the barrier.
__device__ __forceinline__ void wg_barrier() {
    asm volatile("s_waitcnt lgkmcnt(0)\n\ts_barrier" ::: "memory");
}
// DPP sum over the 16-lane row (used ONCE, after the jt loop)
template <int CTRL>
__device__ __forceinline__ float dppf(float v) {
    int iv = __builtin_bit_cast(int, v);
    return __builtin_bit_cast(float,
        __builtin_amdgcn_update_dpp(iv, iv, CTRL, 0xF, 0xF, false));
}
__device__ __forceinline__ float rowsum16(float v) {
    v += dppf<0xB1>(v);    // quad xor1
    v += dppf<0x4E>(v);    // quad xor2
    v += dppf<0x141>(v);   // row_half_mirror
    v += dppf<0x140>(v);   // row_mirror
    return v;
}

// ---------------------------------------------------------------------------
// pack_w: W (q|k|v concat, 320 rows x 256) -> bf16 MFMA-fragment-major layout.
// Q rows pre-scaled by log2(e). grid 40 x 256.   (UNCHANGED)
// ---------------------------------------------------------------------------
__global__ __launch_bounds__(256) void pack_w(
    const float* __restrict__ qw, const float* __restrict__ kw,
    const float* __restrict__ vw, short* __restrict__ wpk) {
    const int g = blockIdx.x * 256 + threadIdx.x;   // 10240 frags
    const int qd = g & 3, m = (g >> 2) & 15, kc = (g >> 6) & 7, ot = g >> 9;
    const int o = 16 * ot + m;
    const float* src;
    float scale = 1.0f;
    if (o < 32)      { src = qw + (size_t)o * Cc; scale = 1.44269504088896f; }
    else if (o < 64) { src = kw + (size_t)(o - 32) * Cc; }
    else             { src = vw + (size_t)(o - 64) * Cc; }
    const float* s8 = src + 32 * kc + 8 * qd;
    uint4 u;
    u.x = pk2(s8[0] * scale, s8[1] * scale);
    u.y = pk2(s8[2] * scale, s8[3] * scale);
    u.z = pk2(s8[4] * scale, s8[5] * scale);
    u.w = pk2(s8[6] * scale, s8[7] * scale);
    *(uint4*)(wpk + (size_t)g * 8) = u;
}

// ---------------------------------------------------------------------------
// proj round-12: 64-n-group x OUTPUT-SPLIT blocks. grid (Nn/64, 2, B) = 512
// blocks (2/CU — TLP restored vs round-11's 256), 256 thr.
//   by=0: q,k (ot 0..3) + V ch 0..127 (ot 4..11), NI=3 o-tiles/wave.
//   by=1: V ch 128..255 (ot 12..19), NI=2.
// xs staged full 64-group (2 verbatim round-3 passes, 33.8 KB). V-epilogue
// writes the block's own 16 KB vstage half (slot bitfield s=4m+nt:
// s>>5=m>>3, (s>>3)&3=(m>>1)&3, s&7=4(m&1)+nt), then one coalesced 16 KB
// uint4 dump to v_b[b][jt] (+by*8192 shorts). q/k epilogue = round-3 with
// nt 0..3. LDS 49 KB -> 2 blocks/CU.
// ---------------------------------------------------------------------------
template <int NI, int OT0, int CTOFF>
__device__ __forceinline__ void proj_body(
    const short* __restrict__ wpk, const short* xs, short* vstage,
    short* __restrict__ q_t, short* __restrict__ k_t,
    int b, int n0, int w, int qd, int m) {
    const int fslot = m * 4 + qd;
    f32x4 acc[NI][4];
#pragma unroll
    for (int i = 0; i < NI; ++i)
#pragma unroll
        for (int nt = 0; nt < 4; ++nt) acc[i][nt] = (f32x4){0.f, 0.f, 0.f, 0.f};

    bf16x8 afc[NI], afn[NI];
#pragma unroll
    for (int i = 0; i < NI; ++i)
        afc[i] = *(const bf16x8*)(
            wpk + ((size_t)((OT0 + 4 * i + w) * 8 + 0) * 64 + fslot) * 8);

    for (int kc = 0; kc < 8; ++kc) {
        if (kc < 7) {
#pragma unroll
            for (int i = 0; i < NI; ++i)
                afn[i] = *(const bf16x8*)(
                    wpk + ((size_t)((OT0 + 4 * i + w) * 8 + kc + 1) * 64 + fslot) * 8);
        }
        bf16x8 bx[4];
#pragma unroll
        for (int nt = 0; nt < 4; ++nt)
            bx[nt] = *(const bf16x8*)&xs[(16 * nt + m) * XST + 32 * kc + 8 * qd];
#pragma unroll
        for (int i = 0; i < NI; ++i)
#pragma unroll
            for (int nt = 0; nt < 4; ++nt)
                acc[i][nt] = __builtin_amdgcn_mfma_f32_16x16x32_bf16(
                    afc[i], bx[nt], acc[i][nt], 0, 0, 0);
#pragma unroll
        for (int i = 0; i < NI; ++i) afc[i] = afn[i];
    }

    // ---- epilogue: C row = 16*ot + 4*qd + rr, col n = n0 + 16*nt + m ----
#pragma unroll
    for (int i = 0; i < NI; ++i) {
        const int ot = OT0 + 4 * i + w;
        if (ot < 4) {
            short* dst = (ot < 2 ? q_t : k_t) + (size_t)b * Nn * Dd;
            const int dbase = (ot & 1) * 16 + 4 * qd;
#pragma unroll
            for (int nt = 0; nt < 4; ++nt) {
                const f32x4 a = acc[i][nt];
                *(uint2*)(dst + (size_t)(n0 + 16 * nt + m) * Dd + dbase) =
                    make_uint2(pk2(a[0], a[1]), pk2(a[2], a[3]));
            }
        } else {
            // V -> vstage: c = 16*(ot-4)+4qd+rr, slots s = 4m+nt (nt 0..3)
            const int gl = (ot - 4 - CTOFF) * 2 + (m >> 3);
            const int base = (gl * 64 + ((m >> 1) & 3) * 16 + 4 * qd) * 8 + 4 * (m & 1);
#pragma unroll
            for (int rr = 0; rr < 4; ++rr)
                *(uint2*)&vstage[base + rr * 8] = make_uint2(
                    pk2(acc[i][0][rr], acc[i][1][rr]),
                    pk2(acc[i][2][rr], acc[i][3][rr]));
        }
    }
}

__global__ __launch_bounds__(256) void proj(
    const float* __restrict__ x, const short* __restrict__ wpk,
    short* __restrict__ q_t, short* __restrict__ k_t, short* __restrict__ v_b) {
    __shared__ alignas(16) short xs[64 * XST];    // 33.8 KB
    __shared__ alignas(16) short vstage[8192];    // 16 KB (this block's half)
    const int b  = blockIdx.z;
    const int by = blockIdx.y;
    const int jt = blockIdx.x;
    const int n0 = jt * 64;
    const int tid = threadIdx.x;
    const int w = tid >> 6;
    const int lane = tid & 63, qd = lane >> 4, m = lane & 15;

    // ---- stage x^T 64-group (2 verbatim round-3 passes) ----
#pragma unroll
    for (int p = 0; p < 2; ++p) {
        const int n = tid & 31, cg = tid >> 5;
        const float* xp = x + ((size_t)b * Cc + 32 * cg) * Nn + n0 + 32 * p + n;
        float xv[32];
#pragma unroll
        for (int i = 0; i < 32; ++i) xv[i] = xp[(size_t)i * Nn];
        short* row = xs + (32 * p + n) * XST + 32 * cg;
#pragma unroll
        for (int u4 = 0; u4 < 4; ++u4)
            *(uint4*)(row + 8 * u4) = make_uint4(
                pk2(xv[8*u4+0], xv[8*u4+1]), pk2(xv[8*u4+2], xv[8*u4+3]),
                pk2(xv[8*u4+4], xv[8*u4+5]), pk2(xv[8*u4+6], xv[8*u4+7]));
    }
    __syncthreads();

    if (by == 0)
        proj_body<3, 0, 0>(wpk, xs, vstage, q_t, k_t, b, n0, w, qd, m);
    else
        proj_body<2, 12, 8>(wpk, xs, vstage, q_t, k_t, b, n0, w, qd, m);

    __syncthreads();   // vstage complete

    // ---- coalesced dump: this block's contiguous 16 KB of v_pk[b][jt] ----
    {
        uint4* dst = (uint4*)(v_b + (size_t)(b * 64 + jt) * 16384 + by * 8192);
        const uint4* srcv = (const uint4*)vstage;
#pragma unroll
        for (int i = 0; i < 4; ++i)
            dst[tid + 256 * i] = srcv[tid + 256 * i];
    }
}

// ---------------------------------------------------------------------------
// attn: EXACT round-9 kernel (verified 54.1-54.9 us). Flash attention, 64
// q-rows x 256 ch, 256 blocks x 512 thr (8 waves), intra-phase pipeline:
// phase(j) = { QK(j+1) MFMA ; PV(j) from p_s[cur] ; exp(j+1) ; write
// p_s[nxt] ; lgkm-barrier }. K prefetch 2 tiles ahead, V 1 phase ahead.
// ---------------------------------------------------------------------------
__global__ __launch_bounds__(512) void attn(
    const float* __restrict__ x, const short* __restrict__ q_t,
    const short* __restrict__ k_t, const short* __restrict__ v_b,
    const float* __restrict__ gamma, float* __restrict__ out) {
    __shared__ alignas(16) char pool[34304];
    float* l_s = (float*)(pool + 33792);    // [2][64] f32
    float* o_t = (float*)pool;              // [64][132] f32 epilogue overlay
    short* buf0 = (short*)pool;             // p_s parity 0 (even tiles)
    short* buf1 = (short*)(pool + 9216);    // p_s parity 1 (odd tiles)

    const int fb  = blockIdx.x;             // 0..255
    const int xcd = fb & 7;
    const int b   = xcd >> 1;
    const int i0  = (((xcd & 1) << 5) | (fb >> 3)) << 6;
    const int tid = threadIdx.x;
    const int w = tid >> 6, lane = tid & 63;
    const int qd = lane >> 4, m = lane & 15;
    const int rt = w & 3, kh = w >> 2;

    // loop-invariant Q fragment (rows i0+16rt+m)
    const bf16x8 af = *(const bf16x8*)(
        q_t + ((size_t)b * Nn + i0 + 16 * rt + m) * Dd + 8 * qd);

    // K frag base: tile jt at kf + jt*2048 (+512 for second 16-key subtile)
    const short* kf = k_t + (size_t)b * Nn * Dd + (32 * kh + m) * Dd + 8 * qd;
    // V frag base: wave w owns frag-groups 4w..4w+3; tile jt at +jt*16384
    const short* vw = v_b + (size_t)b * (64 * 32 * 64 * 8) + (4 * w) * 512 + lane * 8;

    // prologue loads: K(0),K(1); V(0)
    bf16x8 bkA0 = *(const bf16x8*)(kf);
    bf16x8 bkA1 = *(const bf16x8*)(kf + 512);
    bf16x8 bkB0 = *(const bf16x8*)(kf + 2048);
    bf16x8 bkB1 = *(const bf16x8*)(kf + 2560);
    bf16x8 vfA[2][2], vfB[2][2];
#pragma unroll
    for (int ct = 0; ct < 2; ++ct)
#pragma unroll
        for (int kc = 0; kc < 2; ++kc)
            vfA[ct][kc] = *(const bf16x8*)(vw + (2 * ct + kc) * 512);

    f32x4 oacc[4][2];
#pragma unroll
    for (int mt = 0; mt < 4; ++mt)
#pragma unroll
        for (int ct = 0; ct < 2; ++ct) oacc[mt][ct] = (f32x4){0.f, 0.f, 0.f, 0.f};
    float l_i[4] = {0.f, 0.f, 0.f, 0.f};

    // ---- prologue: QK(0) + exp -> buf0 ----
    {
        const f32x4 s0 = __builtin_amdgcn_mfma_f32_16x16x32_bf16(
            af, bkA0, (f32x4){0.f, 0.f, 0.f, 0.f}, 0, 0, 0);
        const f32x4 s1 = __builtin_amdgcn_mfma_f32_16x16x32_bf16(
            af, bkA1, (f32x4){0.f, 0.f, 0.f, 0.f}, 0, 0, 0);
        bkA0 = *(const bf16x8*)(kf + 4096);          // K(2)
        bkA1 = *(const bf16x8*)(kf + 4096 + 512);
#pragma unroll
        for (int rr = 0; rr < 4; ++rr) {
            const float p0 = fexp2(s0[rr]);
            const float p1 = fexp2(s1[rr]);
            l_i[rr] += p0 + p1;
            *(unsigned*)&buf0[(16 * rt + 4 * qd + rr) * 72 + 4 * m + 2 * kh] =
                pk2(p0, p1);
        }
        wg_barrier();
    }

    const short* kpre = kf + 3 * 2048;   // K(2j2+3) in phase A
    const short* vpre = vw + 16384;      // V(2j2+1) in phase A

    for (int j2 = 0; j2 < 31; ++j2) {
        // ===== phase A: QK(2j2+1) ; PV(2j2) buf0/vfA ; exp -> buf1 =====
        {
            const f32x4 s0 = __builtin_amdgcn_mfma_f32_16x16x32_bf16(
                af, bkB0, (f32x4){0.f, 0.f, 0.f, 0.f}, 0, 0, 0);
            const f32x4 s1 = __builtin_amdgcn_mfma_f32_16x16x32_bf16(
                af, bkB1, (f32x4){0.f, 0.f, 0.f, 0.f}, 0, 0, 0);
            bkB0 = *(const bf16x8*)(kpre);           // K(2j2+3)
            bkB1 = *(const bf16x8*)(kpre + 512);
#pragma unroll
            for (int ct = 0; ct < 2; ++ct)           // V(2j2+1) -> vfB
#pragma unroll
                for (int kc = 0; kc < 2; ++kc)
                    vfB[ct][kc] = *(const bf16x8*)(vpre + (2 * ct + kc) * 512);
            __builtin_amdgcn_s_setprio(1);
#pragma unroll
            for (int kc = 0; kc < 2; ++kc) {         // PV(2j2)
                bf16x8 pa[4];
#pragma unroll
                for (int mt = 0; mt < 4; ++mt)
                    pa[mt] = *(const bf16x8*)&buf0[(16 * mt + m) * 72 + 32 * kc + 8 * qd];
#pragma unroll
                for (int ct = 0; ct < 2; ++ct)
#pragma unroll
                    for (int mt = 0; mt < 4; ++mt)
                        oacc[mt][ct] = __builtin_amdgcn_mfma_f32_16x16x32_bf16(
                            pa[mt], vfA[ct][kc], oacc[mt][ct], 0, 0, 0);
            }
            __builtin_amdgcn_s_setprio(0);
#pragma unroll
            for (int rr = 0; rr < 4; ++rr) {         // exp(2j2+1) -> buf1
                const float p0 = fexp2(s0[rr]);
                const float p1 = fexp2(s1[rr]);
                l_i[rr] += p0 + p1;
                *(unsigned*)&buf1[(16 * rt + 4 * qd + rr) * 72 + 4 * m + 2 * kh] =
                    pk2(p0, p1);
            }
            wg_barrier();
        }
        // ===== phase B: QK(2j2+2) ; PV(2j2+1) buf1/vfB ; exp -> buf0 =====
        {
            const f32x4 s0 = __builtin_amdgcn_mfma_f32_16x16x32_bf16(
                af, bkA0, (f32x4){0.f, 0.f, 0.f, 0.f}, 0, 0, 0);
            const f32x4 s1 = __builtin_amdgcn_mfma_f32_16x16x32_bf16(
                af, bkA1, (f32x4){0.f, 0.f, 0.f, 0.f}, 0, 0, 0);
            if (j2 < 30) {                           // K(2j2+4) (skip OOB tail)
                bkA0 = *(const bf16x8*)(kpre + 2048);
                bkA1 = *(const bf16x8*)(kpre + 2560);
            }
#pragma unroll
            for (int ct = 0; ct < 2; ++ct)           // V(2j2+2) -> vfA
#pragma unroll
                for (int kc = 0; kc < 2; ++kc)
                    vfA[ct][kc] = *(const bf16x8*)(vpre + 16384 + (2 * ct + kc) * 512);
            __builtin_amdgcn_s_setprio(1);
#pragma unroll
            for (int kc = 0; kc < 2; ++kc) {         // PV(2j2+1)
                bf16x8 pa[4];
#pragma unroll
                for (int mt = 0; mt < 4; ++mt)
                    pa[mt] = *(const bf16x8*)&buf1[(16 * mt + m) * 72 + 32 * kc + 8 * qd];
#pragma unroll
                for (int ct = 0; ct < 2; ++ct)
#pragma unroll
                    for (int mt = 0; mt < 4; ++mt)
                        oacc[mt][ct] = __builtin_amdgcn_mfma_f32_16x16x32_bf16(
                            pa[mt], vfB[ct][kc], oacc[mt][ct], 0, 0, 0);
            }
            __builtin_amdgcn_s_setprio(0);
#pragma unroll
            for (int rr = 0; rr < 4; ++rr) {         // exp(2j2+2) -> buf0
                const float p0 = fexp2(s0[rr]);
                const float p1 = fexp2(s1[rr]);
                l_i[rr] += p0 + p1;
                *(unsigned*)&buf0[(16 * rt + 4 * qd + rr) * 72 + 4 * m + 2 * kh] =
                    pk2(p0, p1);
            }
            wg_barrier();
        }
        kpre += 4096;
        vpre += 32768;
    }

    // ---- tail A: QK(63) ; PV(62) buf0/vfA ; exp -> buf1 ----
    {
        const f32x4 s0 = __builtin_amdgcn_mfma_f32_16x16x32_bf16(
            af, bkB0, (f32x4){0.f, 0.f, 0.f, 0.f}, 0, 0, 0);
        const f32x4 s1 = __builtin_amdgcn_mfma_f32_16x16x32_bf16(
            af, bkB1, (f32x4){0.f, 0.f, 0.f, 0.f}, 0, 0, 0);
#pragma unroll
        for (int ct = 0; ct < 2; ++ct)               // V(63) -> vfB
#pragma unroll
            for (int kc = 0; kc < 2; ++kc)
                vfB[ct][kc] = *(const bf16x8*)(vpre + (2 * ct + kc) * 512);
        __builtin_amdgcn_s_setprio(1);
#pragma unroll
        for (int kc = 0; kc < 2; ++kc) {             // PV(62)
            bf16x8 pa[4];
#pragma unroll
            for (int mt = 0; mt < 4; ++mt)
                pa[mt] = *(const bf16x8*)&buf0[(16 * mt + m) * 72 + 32 * kc + 8 * qd];
#pragma unroll
            for (int ct = 0; ct < 2; ++ct)
#pragma unroll
                for (int mt = 0; mt < 4; ++mt)
                    oacc[mt][ct] = __builtin_amdgcn_mfma_f32_16x16x32_bf16(
                        pa[mt], vfA[ct][kc], oacc[mt][ct], 0, 0, 0);
        }
        __builtin_amdgcn_s_setprio(0);
#pragma unroll
        for (int rr = 0; rr < 4; ++rr) {             // exp(63) -> buf1
            const float p0 = fexp2(s0[rr]);
            const float p1 = fexp2(s1[rr]);
            l_i[rr] += p0 + p1;
            *(unsigned*)&buf1[(16 * rt + 4 * qd + rr) * 72 + 4 * m + 2 * kh] =
                pk2(p0, p1);
        }
        wg_barrier();
    }
    // ---- tail B: PV(63) buf1/vfB ----
    {
        __builtin_amdgcn_s_setprio(1);
#pragma unroll
        for (int kc = 0; kc < 2; ++kc) {
            bf16x8 pa[4];
#pragma unroll
            for (int mt = 0; mt < 4; ++mt)
                pa[mt] = *(const bf16x8*)&buf1[(16 * mt + m) * 72 + 32 * kc + 8 * qd];
#pragma unroll
            for (int ct = 0; ct < 2; ++ct)
#pragma unroll
                for (int mt = 0; mt < 4; ++mt)
                    oacc[mt][ct] = __builtin_amdgcn_mfma_f32_16x16x32_bf16(
                        pa[mt], vfB[ct][kc], oacc[mt][ct], 0, 0, 0);
        }
        __builtin_amdgcn_s_setprio(0);
    }

    // final l reduction: per kh-half row sums, combined in epilogue
#pragma unroll
    for (int rr = 0; rr < 4; ++rr) l_i[rr] = rowsum16(l_i[rr]);
    if (m == 0)
        *(f32x4*)&l_s[kh * 64 + 16 * rt + 4 * qd] =
            (f32x4){l_i[0], l_i[1], l_i[2], l_i[3]};
    __syncthreads();   // l published; loop LDS dead -> o_t overlay safe

    // ---- epilogue: transpose O via LDS overlay, out = gamma*O/l + x ----
    const float g = gamma[0];
    const int i = tid & 63, cg8 = tid >> 6;   // row, ch-group
    const float linv = 1.0f / (l_s[i] + l_s[64 + i]);
#pragma unroll
    for (int ps = 0; ps < 2; ++ps) {
        if (ps) __syncthreads();
        // pass ps: channels 32w + 16ps + m  -> compact col cc = 16w + m
#pragma unroll
        for (int mt = 0; mt < 4; ++mt)
#pragma unroll
            for (int rr = 0; rr < 4; ++rr)
                o_t[(16 * mt + 4 * qd + rr) * 132 + 16 * w + m] = oacc[mt][ps][rr];
        __syncthreads();
#pragma unroll
        for (int u = 0; u < 4; ++u) {
            const f32x4 v4 = *(const f32x4*)&o_t[i * 132 + 16 * cg8 + 4 * u];
#pragma unroll
            for (int e = 0; e < 4; ++e) {
                const int c = 32 * cg8 + 16 * ps + 4 * u + e;
                const size_t gidx = ((size_t)b * Cc + c) * Nn + i0 + i;
                out[gidx] = g * v4[e] * linv + x[gidx];
            }
        }
    }
}

// ---------------------------------------------------------------------------
extern "C" void kernel_launch(void* const* d_in, const int* in_sizes, int n_in,
                              void* d_out, int out_size, void* d_ws, size_t ws_size,
                              hipStream_t stream) {
    const float* x     = (const float*)d_in[0];
    const float* qw    = (const float*)d_in[1];
    const float* kw    = (const float*)d_in[2];
    const float* vw    = (const float*)d_in[3];
    const float* gamma = (const float*)d_in[4];
    float* out = (float*)d_out;

    short* q_t = (short*)d_ws;                       // [b][n][32] bf16, 1 MB
    short* k_t = q_t + (size_t)Bb * Nn * Dd;         // [b][n][32] bf16, 1 MB
    short* v_b = k_t + (size_t)Bb * Nn * Dd;         // fragment-major V, 8.4 MB
    short* wpk = v_b + (size_t)Bb * Cc * Nn;         // 160 KB packed W

    pack_w<<<dim3(40), 256, 0, stream>>>(qw, kw, vw, wpk);
    proj<<<dim3(Nn / 64, 2, Bb), 256, 0, stream>>>(x, wpk, q_t, k_t, v_b);
    attn<<<dim3(256), 512, 0, stream>>>(x, q_t, k_t, v_b, gamma, out);
}